// Round 10
// baseline (2071.291 us; speedup 1.0000x reference)
//
#include <hip/hip_runtime.h>

typedef unsigned short u16;
typedef unsigned int u32;
typedef __attribute__((ext_vector_type(8))) short bf16x8;   // 8 bf16 = 4 VGPRs
typedef __attribute__((ext_vector_type(4))) float f32x4;
typedef __attribute__((ext_vector_type(4))) u16 u16x4;
typedef __attribute__((ext_vector_type(8))) u16 u16x8;

#define N_NODES 20000
#define N_EDGES 320000
#define F_IN 128
#define HID 256
#define OUT_F 32
#define N_LAYERS 30
#define N_GRAPHS 16
#define ELLCAP 64

// ---------------- bf16 split helpers ----------------
__device__ __forceinline__ u16 f32_to_bf16(float f) {
    u32 u = __float_as_uint(f);
    u32 r = (u + 0x7FFFu + ((u >> 16) & 1u)) >> 16;   // round-to-nearest-even
    return (u16)r;
}
__device__ __forceinline__ float bf16_to_f32(u16 h) {
    return __uint_as_float(((u32)h) << 16);
}

// ---------------- graph build ----------------
// fill_ell also produces the degree: cursor's final value == in-degree at dst.
// ell_col is pre-zeroed; unfilled slots stay 0 (node 0: valid, masked off in agg).
__global__ void fill_ell_kernel(const int* __restrict__ src, const int* __restrict__ dst,
                                int* __restrict__ cursor, u16* __restrict__ ell_col, int E) {
    int e = blockIdx.x * blockDim.x + threadIdx.x;
    if (e >= E) return;
    int s = src[e], d = dst[e];
    int slot = atomicAdd(&cursor[d], 1);
    if (slot < ELLCAP) ell_col[d * ELLCAP + slot] = (u16)s;
}

__global__ void dinv_kernel(const int* __restrict__ cnt, float* __restrict__ dinv, int n) {
    int i = blockIdx.x * blockDim.x + threadIdx.x;
    if (i < n) dinv[i] = rsqrtf((float)(cnt[i] + 1));  // +1 self loop
}

// x' = dinv ⊙ x  (pre-scaled gather source for layer 1)
__global__ void prescale_x_kernel(const float* __restrict__ x, const float* __restrict__ dinv,
                                  float* __restrict__ xs, int total) {
    int i = blockIdx.x * 256 + threadIdx.x;
    if (i < total) xs[i] = x[i] * dinv[i >> 7];   // F_IN = 128
}

// ---------------- weight split+transpose (LDS-tiled, coalesced writes) ----------------
// W [L][K][N] -> Th/Tl [L][N][K]; 32x32 tiles.
__global__ __launch_bounds__(256) void transpose_split_tiled(const float* __restrict__ W,
                                                             u16* __restrict__ Th, u16* __restrict__ Tl,
                                                             int K, int N) {
    __shared__ float tile[32][33];
    const int l = blockIdx.y;
    const int ntn = N >> 5;
    const int kt = blockIdx.x / ntn, ntile = blockIdx.x % ntn;
    const float* Wl = W + (size_t)l * K * N;
    u16* Thl = Th + (size_t)l * K * N;
    u16* Tll = Tl + (size_t)l * K * N;
    const int r8 = threadIdx.x >> 5, c = threadIdx.x & 31;
    #pragma unroll
    for (int rr = 0; rr < 4; ++rr) {
        int r = rr * 8 + r8;
        tile[r][c] = Wl[(size_t)(kt * 32 + r) * N + ntile * 32 + c];
    }
    __syncthreads();
    #pragma unroll
    for (int rr = 0; rr < 4; ++rr) {
        int n = rr * 8 + r8;                 // transposed row (N dim)
        float v = tile[c][n];                // W[k=kt*32+c][n]
        u16 hb = f32_to_bf16(v);
        u16 lb = f32_to_bf16(v - bf16_to_f32(hb));
        size_t o = (size_t)(ntile * 32 + n) * K + kt * 32 + c;
        Thl[o] = hb;
        Tll[o] = lb;
    }
}

// ---------------- feature-split aggregation ----------------
// g[d] = dinv[d] * (sum_{s in N(d)} hs[s] + hs[d]), hs pre-scaled by dinv.
// Block = 32 nodes x one 32-feature chunk; fc = blockIdx & (CHUNKS-1): round-robin
// block->XCD dispatch pins one feature slice (2.56 MB) per XCD L2.
// 8 lanes/node, f32x4/lane. Full 8-batches only (zero-padded ELL, masked final adds)
// -> one waitcnt per batch, no serial-latency tail. Depth-2 software pipeline.
template <int F>
__global__ __launch_bounds__(256) void agg_fsplit(const float* __restrict__ hs,
                                                  const u16* __restrict__ ell_col,
                                                  const int* __restrict__ cnt,
                                                  const float* __restrict__ dinv,
                                                  u16* __restrict__ ghi, u16* __restrict__ glo) {
    constexpr int CHUNKS = F / 32;
    __shared__ u16 cols[32 * ELLCAP];
    const int blk = blockIdx.x;
    const int fc = blk & (CHUNKS - 1);
    const int grp = blk / CHUNKS;
    const int node0 = grp * 32;
    const int tid = threadIdx.x;
    *(u16x8*)&cols[tid * 8] = *(const u16x8*)&ell_col[(size_t)node0 * ELLCAP + tid * 8];
    const int g = tid >> 3, sub = tid & 7;
    const int node = node0 + g;
    const int f = fc * 32 + sub * 4;
    int c = cnt[node]; c = c < ELLCAP ? c : ELLCAP;
    const float dd = dinv[node];
    f32x4 acc = *(const f32x4*)(hs + (size_t)node * F + f);   // self loop (pre-scaled)
    __syncthreads();
    const u16* cl = &cols[g * ELLCAP];
    const int nb = (c + 7) >> 3;   // number of 8-batches (last one masked)
    if (nb > 0) {
        const f32x4 zero = {0.f, 0.f, 0.f, 0.f};
        f32x4 vbuf[8];
        u16x8 cc = *(const u16x8*)&cl[0];
        #pragma unroll
        for (int j = 0; j < 8; ++j) vbuf[j] = *(const f32x4*)(hs + (size_t)cc[j] * F + f);
        int base = 0;
        for (int b = 1; b < nb; ++b) {
            u16x8 cn = *(const u16x8*)&cl[b * 8];
            f32x4 vn[8];
            #pragma unroll
            for (int j = 0; j < 8; ++j) vn[j] = *(const f32x4*)(hs + (size_t)cn[j] * F + f);
            #pragma unroll
            for (int j = 0; j < 8; ++j) acc += vbuf[j];   // non-final batches are full
            base += 8;
            #pragma unroll
            for (int j = 0; j < 8; ++j) vbuf[j] = vn[j];
        }
        #pragma unroll
        for (int j = 0; j < 8; ++j) acc += (base + j < c) ? vbuf[j] : zero;  // masked final batch
    }
    u16x4 vh, vl;
    #pragma unroll
    for (int i = 0; i < 4; ++i) {
        float v = acc[i] * dd;
        u16 hb = f32_to_bf16(v);
        vh[i] = hb;
        vl[i] = f32_to_bf16(v - bf16_to_f32(hb));
    }
    *(u16x4*)(ghi + (size_t)node * F + f) = vh;
    *(u16x4*)(glo + (size_t)node * F + f) = vl;
}

// ---------------- split-bf16 MFMA GEMM, barrier-free register streaming ----------------
// C[M][N] = rowscale[m] * relu((Ah+Al)[M][K] @ (Bh+Bl)^T + bias), B transposed [N][K].
// Block = 512 threads = 8 waves (2 wm x 4 wn), covers 128 m x 256 n (full N) -> A read
// EXACTLY once per layer (20.5 MB, L3-resident), B (512 KB) L2-hot in every XCD.
// MFMA fragments (16 B/lane; lanes 0-15/16-31/32-47/48-63 = one 64 B row-segment each)
// are loaded straight from global: no LDS, no __syncthreads, no vmcnt(0) drains.
// Fragment k-order identical to the former LDS path -> bit-identical accumulation.
__global__ __launch_bounds__(512, 2) void gemm_bias_relu(const u16* __restrict__ Ah, const u16* __restrict__ Al,
                                                         const u16* __restrict__ Bh, const u16* __restrict__ Bl,
                                                         const float* __restrict__ bias,
                                                         const float* __restrict__ rowscale,
                                                         float* __restrict__ C, int M, int K, int N) {
    const int tid = threadIdx.x;
    const int wave = tid >> 6, lane = tid & 63;
    const int wm = wave >> 2, wn = wave & 3;
    const int row0 = blockIdx.x * 128;
    const int l16 = lane & 15;
    const int kloff = (lane >> 4) * 8;    // k offset of this lane's 16 B piece within a 32-k step
    int rm[4];
    #pragma unroll
    for (int mt = 0; mt < 4; ++mt) {
        int r = row0 + wm * 64 + mt * 16 + l16;
        rm[mt] = r < M ? r : (M - 1);     // tail rows read row M-1; writes guarded
    }
    int nb[4];
    #pragma unroll
    for (int nt = 0; nt < 4; ++nt) nb[nt] = wn * 64 + nt * 16 + l16;

    f32x4 acc[4][4] = {};
    const int ksteps = K >> 5;
    for (int s = 0; s < ksteps; ++s) {
        const int kb = s * 32 + kloff;
        bf16x8 ah[4], al[4], bh[4], bl[4];
        #pragma unroll
        for (int mt = 0; mt < 4; ++mt) {
            ah[mt] = *(const bf16x8*)(Ah + (size_t)rm[mt] * K + kb);
            al[mt] = *(const bf16x8*)(Al + (size_t)rm[mt] * K + kb);
        }
        #pragma unroll
        for (int nt = 0; nt < 4; ++nt) {
            bh[nt] = *(const bf16x8*)(Bh + (size_t)nb[nt] * K + kb);
            bl[nt] = *(const bf16x8*)(Bl + (size_t)nb[nt] * K + kb);
        }
        #pragma unroll
        for (int mt = 0; mt < 4; ++mt) {
            #pragma unroll
            for (int nt = 0; nt < 4; ++nt) {
                acc[mt][nt] = __builtin_amdgcn_mfma_f32_16x16x32_bf16(ah[mt], bh[nt], acc[mt][nt], 0, 0, 0);
                acc[mt][nt] = __builtin_amdgcn_mfma_f32_16x16x32_bf16(ah[mt], bl[nt], acc[mt][nt], 0, 0, 0);
                acc[mt][nt] = __builtin_amdgcn_mfma_f32_16x16x32_bf16(al[mt], bh[nt], acc[mt][nt], 0, 0, 0);
            }
        }
    }
    // epilogue: bias + relu (+ dinv row scale); C/D layout col=lane&15, row=(lane>>4)*4+r
    #pragma unroll
    for (int mt = 0; mt < 4; ++mt) {
        int gr = row0 + wm * 64 + mt * 16 + ((lane >> 4) << 2);
        #pragma unroll
        for (int r = 0; r < 4; ++r) {
            if (gr + r >= M) continue;
            float sc = rowscale ? rowscale[gr + r] : 1.f;
            #pragma unroll
            for (int nt = 0; nt < 4; ++nt) {
                int gc = wn * 64 + nt * 16 + l16;
                C[(size_t)(gr + r) * N + gc] = sc * fmaxf(acc[mt][nt][r] + bias[gc], 0.f);
            }
        }
    }
}

// ---------------- pooling ----------------
#define POOL_CHUNK 32
__global__ __launch_bounds__(256) void pool_kernel(const float* __restrict__ h,
                                                   const int* __restrict__ batch,
                                                   float* __restrict__ pool_sum) {
    int f = threadIdx.x;
    int start = blockIdx.x * POOL_CHUNK;
    int end = start + POOL_CHUNK; end = end < N_NODES ? end : N_NODES;
    if (start >= N_NODES) return;
    int gcur = batch[start];
    float acc = 0.f;
    for (int i = start; i < end; ++i) {
        int g = batch[i];
        if (g != gcur) { atomicAdd(&pool_sum[gcur * HID + f], acc); acc = 0.f; gcur = g; }
        acc += h[(size_t)i * HID + f];
    }
    atomicAdd(&pool_sum[gcur * HID + f], acc);
}

__device__ int lb_int(const int* __restrict__ a, int n, int v) {
    int lo = 0, hi = n;
    while (lo < hi) {
        int mid = (lo + hi) >> 1;
        if (a[mid] < v) lo = mid + 1; else hi = mid;
    }
    return lo;
}

__global__ void final_linear_kernel(const float* __restrict__ pool_sum,
                                    const int* __restrict__ batch,
                                    const float* __restrict__ Wlin,
                                    const float* __restrict__ blin,
                                    float* __restrict__ out) {
    int idx = blockIdx.x * blockDim.x + threadIdx.x;
    if (idx >= N_GRAPHS * OUT_F) return;
    int g = idx / OUT_F, o = idx % OUT_F;
    int lo = lb_int(batch, N_NODES, g);
    int hi = lb_int(batch, N_NODES, g + 1);
    float cinv = 1.f / fmaxf((float)(hi - lo), 1.f);
    float s = blin[o];
    for (int k = 0; k < HID; ++k) s += (pool_sum[g * HID + k] * cinv) * Wlin[k * OUT_F + o];
    out[idx] = s;
}

// ---------------- launch ----------------
static inline size_t align_up(size_t x, size_t a) { return (x + a - 1) & ~(a - 1); }

extern "C" void kernel_launch(void* const* d_in, const int* in_sizes, int n_in,
                              void* d_out, int out_size, void* d_ws, size_t ws_size,
                              hipStream_t stream) {
    const float* x     = (const float*)d_in[0];
    const int*   elist = (const int*)d_in[1];   // [2, E]
    const int*   batch = (const int*)d_in[2];
    const float* W1    = (const float*)d_in[3];
    const float* b1    = (const float*)d_in[4];
    const float* Wm    = (const float*)d_in[5];
    const float* bm    = (const float*)d_in[6];
    const float* Wlin  = (const float*)d_in[7];
    const float* blin  = (const float*)d_in[8];
    float* outp = (float*)d_out;

    const int* srcA = elist;
    const int* dstA = elist + N_EDGES;

    char* ws = (char*)d_ws;
    size_t off = 0;
    float* h      = (float*)(ws + off); off = align_up(off + sizeof(float) * N_NODES * HID, 1024);
    float* xs     = (float*)(ws + off); off = align_up(off + sizeof(float) * N_NODES * F_IN, 1024);
    u16*   g_hi   = (u16*)(ws + off);   off = align_up(off + sizeof(u16) * N_NODES * HID, 1024);
    u16*   g_lo   = (u16*)(ws + off);   off = align_up(off + sizeof(u16) * N_NODES * HID, 1024);
    u16*   W1T_h  = (u16*)(ws + off);   off = align_up(off + sizeof(u16) * F_IN * HID, 1024);
    u16*   W1T_l  = (u16*)(ws + off);   off = align_up(off + sizeof(u16) * F_IN * HID, 1024);
    u16*   WmT_h  = (u16*)(ws + off);   off = align_up(off + sizeof(u16) * (N_LAYERS - 1) * HID * HID, 1024);
    u16*   WmT_l  = (u16*)(ws + off);   off = align_up(off + sizeof(u16) * (N_LAYERS - 1) * HID * HID, 1024);
    int*   cursor = (int*)(ws + off);   off = align_up(off + sizeof(int) * N_NODES, 1024);
    float* dinv   = (float*)(ws + off); off = align_up(off + sizeof(float) * N_NODES, 1024);
    u16*   ell_col = (u16*)(ws + off);  off = align_up(off + sizeof(u16) * N_NODES * ELLCAP, 1024);
    float* pool_sum = (float*)(ws + off); off = align_up(off + sizeof(float) * N_GRAPHS * HID, 1024);

    hipMemsetAsync(cursor, 0, sizeof(int) * N_NODES, stream);
    hipMemsetAsync(ell_col, 0, sizeof(u16) * N_NODES * ELLCAP, stream);  // pad slots -> node 0 (masked)
    hipMemsetAsync(pool_sum, 0, sizeof(float) * N_GRAPHS * HID, stream);

    fill_ell_kernel<<<(N_EDGES + 255) / 256, 256, 0, stream>>>(srcA, dstA, cursor, ell_col, N_EDGES);
    dinv_kernel<<<(N_NODES + 255) / 256, 256, 0, stream>>>(cursor, dinv, N_NODES);
    prescale_x_kernel<<<(N_NODES * F_IN + 255) / 256, 256, 0, stream>>>(x, dinv, xs, N_NODES * F_IN);

    transpose_split_tiled<<<dim3((F_IN / 32) * (HID / 32), 1), 256, 0, stream>>>(W1, W1T_h, W1T_l, F_IN, HID);
    transpose_split_tiled<<<dim3((HID / 32) * (HID / 32), N_LAYERS - 1), 256, 0, stream>>>(Wm, WmT_h, WmT_l, HID, HID);

    const int n_row_tiles = (N_NODES + 127) / 128;   // 157 blocks, 512 threads each
    // layer 1: g = agg(xs) [K=128]; h' = dinv * relu(g @ W1 + b1)
    agg_fsplit<F_IN><<<(N_NODES / 32) * (F_IN / 32), 256, 0, stream>>>(xs, ell_col, cursor, dinv, g_hi, g_lo);
    gemm_bias_relu<<<n_row_tiles, 512, 0, stream>>>(g_hi, g_lo, W1T_h, W1T_l, b1, dinv, h, N_NODES, F_IN, HID);
    // middle layers: g = agg(h'); h' = dinv * relu(g @ W + b)  (last: unscaled for pooling)
    for (int l = 0; l < N_LAYERS - 1; ++l) {
        agg_fsplit<HID><<<(N_NODES / 32) * (HID / 32), 256, 0, stream>>>(h, ell_col, cursor, dinv, g_hi, g_lo);
        const float* rs = (l == N_LAYERS - 2) ? nullptr : dinv;
        gemm_bias_relu<<<n_row_tiles, 512, 0, stream>>>(g_hi, g_lo, WmT_h + (size_t)l * HID * HID,
                                                        WmT_l + (size_t)l * HID * HID,
                                                        bm + (size_t)l * HID, rs, h, N_NODES, HID, HID);
    }
    pool_kernel<<<(N_NODES + POOL_CHUNK - 1) / POOL_CHUNK, 256, 0, stream>>>(h, batch, pool_sum);
    final_linear_kernel<<<2, 256, 0, stream>>>(pool_sum, batch, Wlin, blin, outp);
}

// Round 11
// 1842.631 us; speedup vs baseline: 1.1241x; 1.1241x over previous
//
#include <hip/hip_runtime.h>

typedef unsigned short u16;
typedef unsigned int u32;
typedef __attribute__((ext_vector_type(8))) short bf16x8;   // 8 bf16 = 4 VGPRs
typedef __attribute__((ext_vector_type(4))) float f32x4;
typedef __attribute__((ext_vector_type(4))) u16 u16x4;
typedef __attribute__((ext_vector_type(8))) u16 u16x8;

#define N_NODES 20000
#define N_EDGES 320000
#define F_IN 128
#define HID 256
#define OUT_F 32
#define N_LAYERS 30
#define N_GRAPHS 16
#define ELLCAP 64

// ---------------- bf16 split helpers ----------------
__device__ __forceinline__ u16 f32_to_bf16(float f) {
    u32 u = __float_as_uint(f);
    u32 r = (u + 0x7FFFu + ((u >> 16) & 1u)) >> 16;   // round-to-nearest-even
    return (u16)r;
}
__device__ __forceinline__ float bf16_to_f32(u16 h) {
    return __uint_as_float(((u32)h) << 16);
}

__device__ __forceinline__ void gl_lds16(const u16* g, u16* l) {
    __builtin_amdgcn_global_load_lds((const u32*)g, (u32*)l, 16, 0, 0);
}

// ---------------- graph build ----------------
// fill_ell also produces the degree: cursor's final value == in-degree at dst.
// ell_col is pre-zeroed; unfilled slots stay 0 (node 0: valid, masked off in agg).
__global__ void fill_ell_kernel(const int* __restrict__ src, const int* __restrict__ dst,
                                int* __restrict__ cursor, u16* __restrict__ ell_col, int E) {
    int e = blockIdx.x * blockDim.x + threadIdx.x;
    if (e >= E) return;
    int s = src[e], d = dst[e];
    int slot = atomicAdd(&cursor[d], 1);
    if (slot < ELLCAP) ell_col[d * ELLCAP + slot] = (u16)s;
}

__global__ void dinv_kernel(const int* __restrict__ cnt, float* __restrict__ dinv, int n) {
    int i = blockIdx.x * blockDim.x + threadIdx.x;
    if (i < n) dinv[i] = rsqrtf((float)(cnt[i] + 1));  // +1 self loop
}

// x' = dinv ⊙ x  (pre-scaled gather source for layer 1)
__global__ void prescale_x_kernel(const float* __restrict__ x, const float* __restrict__ dinv,
                                  float* __restrict__ xs, int total) {
    int i = blockIdx.x * 256 + threadIdx.x;
    if (i < total) xs[i] = x[i] * dinv[i >> 7];   // F_IN = 128
}

// ---------------- weight split+transpose (LDS-tiled, coalesced writes) ----------------
// W [L][K][N] -> Th/Tl [L][N][K]; 32x32 tiles.
__global__ __launch_bounds__(256) void transpose_split_tiled(const float* __restrict__ W,
                                                             u16* __restrict__ Th, u16* __restrict__ Tl,
                                                             int K, int N) {
    __shared__ float tile[32][33];
    const int l = blockIdx.y;
    const int ntn = N >> 5;
    const int kt = blockIdx.x / ntn, ntile = blockIdx.x % ntn;
    const float* Wl = W + (size_t)l * K * N;
    u16* Thl = Th + (size_t)l * K * N;
    u16* Tll = Tl + (size_t)l * K * N;
    const int r8 = threadIdx.x >> 5, c = threadIdx.x & 31;
    #pragma unroll
    for (int rr = 0; rr < 4; ++rr) {
        int r = rr * 8 + r8;
        tile[r][c] = Wl[(size_t)(kt * 32 + r) * N + ntile * 32 + c];
    }
    __syncthreads();
    #pragma unroll
    for (int rr = 0; rr < 4; ++rr) {
        int n = rr * 8 + r8;                 // transposed row (N dim)
        float v = tile[c][n];                // W[k=kt*32+c][n]
        u16 hb = f32_to_bf16(v);
        u16 lb = f32_to_bf16(v - bf16_to_f32(hb));
        size_t o = (size_t)(ntile * 32 + n) * K + kt * 32 + c;
        Thl[o] = hb;
        Tll[o] = lb;
    }
}

// ---------------- feature-split aggregation ----------------
// g[d] = dinv[d] * (sum_{s in N(d)} hs[s] + hs[d]), hs pre-scaled by dinv.
// Block = 32 nodes x one 32-feature chunk; fc = blockIdx & (CHUNKS-1): round-robin
// block->XCD dispatch pins one feature slice (2.56 MB) per XCD L2.
// 8 lanes/node, f32x4/lane. Full 8-batches only (zero-padded ELL, masked final adds)
// -> one waitcnt per batch, no serial-latency tail. Depth-2 software pipeline.
template <int F>
__global__ __launch_bounds__(256) void agg_fsplit(const float* __restrict__ hs,
                                                  const u16* __restrict__ ell_col,
                                                  const int* __restrict__ cnt,
                                                  const float* __restrict__ dinv,
                                                  u16* __restrict__ ghi, u16* __restrict__ glo) {
    constexpr int CHUNKS = F / 32;
    __shared__ u16 cols[32 * ELLCAP];
    const int blk = blockIdx.x;
    const int fc = blk & (CHUNKS - 1);
    const int grp = blk / CHUNKS;
    const int node0 = grp * 32;
    const int tid = threadIdx.x;
    *(u16x8*)&cols[tid * 8] = *(const u16x8*)&ell_col[(size_t)node0 * ELLCAP + tid * 8];
    const int g = tid >> 3, sub = tid & 7;
    const int node = node0 + g;
    const int f = fc * 32 + sub * 4;
    int c = cnt[node]; c = c < ELLCAP ? c : ELLCAP;
    const float dd = dinv[node];
    f32x4 acc = *(const f32x4*)(hs + (size_t)node * F + f);   // self loop (pre-scaled)
    __syncthreads();
    const u16* cl = &cols[g * ELLCAP];
    const int nb = (c + 7) >> 3;   // number of 8-batches (last one masked)
    if (nb > 0) {
        const f32x4 zero = {0.f, 0.f, 0.f, 0.f};
        f32x4 vbuf[8];
        u16x8 cc = *(const u16x8*)&cl[0];
        #pragma unroll
        for (int j = 0; j < 8; ++j) vbuf[j] = *(const f32x4*)(hs + (size_t)cc[j] * F + f);
        int base = 0;
        for (int b = 1; b < nb; ++b) {
            u16x8 cn = *(const u16x8*)&cl[b * 8];
            f32x4 vn[8];
            #pragma unroll
            for (int j = 0; j < 8; ++j) vn[j] = *(const f32x4*)(hs + (size_t)cn[j] * F + f);
            #pragma unroll
            for (int j = 0; j < 8; ++j) acc += vbuf[j];   // non-final batches are full
            base += 8;
            #pragma unroll
            for (int j = 0; j < 8; ++j) vbuf[j] = vn[j];
        }
        #pragma unroll
        for (int j = 0; j < 8; ++j) acc += (base + j < c) ? vbuf[j] : zero;  // masked final batch
    }
    u16x4 vh, vl;
    #pragma unroll
    for (int i = 0; i < 4; ++i) {
        float v = acc[i] * dd;
        u16 hb = f32_to_bf16(v);
        vh[i] = hb;
        vl[i] = f32_to_bf16(v - bf16_to_f32(hb));
    }
    *(u16x4*)(ghi + (size_t)node * F + f) = vh;
    *(u16x4*)(glo + (size_t)node * F + f) = vl;
}

// ---------------- split-bf16 MFMA GEMM + bias + relu (+ optional row scale) ----------------
// C[M][N] = rowscale[m] * relu((Ah+Al)[M][K] @ (Bh+Bl)^T + bias), B transposed [N][K].
// Tile: 128(M) x 128(N) x 64(K). 256 threads = 4 waves (2x2), wave = 64m x 64n (4x4 frags).
// A staged in LDS (32 KB; XOR-swizzled, global_load_lds) -> staged only 2x/layer.
// B (512 KB, L2-hot in every XCD) fragment-loaded DIRECTLY from global: no B LDS,
// no extra barrier-coupled traffic. MFMA chain order identical to R9 -> bit-identical.
// XCD-swizzled 1D grid keeps a row-tile's two n-tiles on one XCD.
#define NCOLT 2   // N/128
__global__ __launch_bounds__(256, 3) void gemm_bias_relu(const u16* __restrict__ Ah, const u16* __restrict__ Al,
                                                         const u16* __restrict__ Bh, const u16* __restrict__ Bl,
                                                         const float* __restrict__ bias,
                                                         const float* __restrict__ rowscale,
                                                         float* __restrict__ C, int M, int K, int N) {
    __shared__ __align__(16) u16 As_h[128 * 64];
    __shared__ __align__(16) u16 As_l[128 * 64];
    const int bid = blockIdx.x;
    const int slot = bid & 7;
    const int j = bid >> 3;
    const int ncol = j & (NCOLT - 1);
    const int rowhi = j / NCOLT;
    const int row_tile = rowhi * 8 + slot;
    const int row0 = row_tile * 128;
    if (row0 >= M) return;
    const int n0 = ncol * 128;
    const int tid = threadIdx.x;
    const int wave = tid >> 6, lane = tid & 63;
    const int wm = wave >> 1, wn = wave & 1;
    const int l16 = lane & 15;
    const int lr = lane >> 3;   // row within 8-row staging group
    const int lc = lane & 7;    // 16B-chunk position within row
    f32x4 acc[4][4] = {};

    for (int k0 = 0; k0 < K; k0 += 64) {
        // stage A hi/lo: 128 rows x 64 k, XOR-swizzled chunks
        #pragma unroll
        for (int q = 0; q < 4; ++q) {
            int rl = (wave * 4 + q) * 8 + lr;
            int ra = row0 + rl; ra = ra < M ? ra : (M - 1);   // clamp tail (rows >= M unused)
            int cg = (lc ^ (rl & 7)) << 3;
            gl_lds16(Ah + (size_t)ra * K + k0 + cg, &As_h[(wave * 4 + q) * 512]);
            gl_lds16(Al + (size_t)ra * K + k0 + cg, &As_l[(wave * 4 + q) * 512]);
        }
        __syncthreads();
        #pragma unroll
        for (int kk = 0; kk < 2; ++kk) {
            const int cidx = kk * 4 + (lane >> 4);
            const int kb = k0 + kk * 32 + (lane >> 4) * 8;
            bf16x8 bhf[4], blf[4];
            #pragma unroll
            for (int nt = 0; nt < 4; ++nt) {
                int nr = n0 + wn * 64 + nt * 16 + l16;
                bhf[nt] = *(const bf16x8*)(Bh + (size_t)nr * K + kb);
                blf[nt] = *(const bf16x8*)(Bl + (size_t)nr * K + kb);
            }
            #pragma unroll
            for (int mt = 0; mt < 4; ++mt) {
                int ml = wm * 64 + mt * 16 + l16;
                int off = ml * 64 + ((cidx ^ (ml & 7)) << 3);
                bf16x8 ah = *(const bf16x8*)&As_h[off];
                bf16x8 al = *(const bf16x8*)&As_l[off];
                #pragma unroll
                for (int nt = 0; nt < 4; ++nt) {
                    acc[mt][nt] = __builtin_amdgcn_mfma_f32_16x16x32_bf16(ah, bhf[nt], acc[mt][nt], 0, 0, 0);
                    acc[mt][nt] = __builtin_amdgcn_mfma_f32_16x16x32_bf16(ah, blf[nt], acc[mt][nt], 0, 0, 0);
                    acc[mt][nt] = __builtin_amdgcn_mfma_f32_16x16x32_bf16(al, bhf[nt], acc[mt][nt], 0, 0, 0);
                }
            }
        }
        __syncthreads();
    }
    // epilogue: bias + relu (+ dinv row scale); C/D layout col=lane&15, row=(lane>>4)*4+r
    #pragma unroll
    for (int mt = 0; mt < 4; ++mt) {
        int gr = row0 + wm * 64 + mt * 16 + ((lane >> 4) << 2);
        #pragma unroll
        for (int r = 0; r < 4; ++r) {
            if (gr + r >= M) continue;
            float sc = rowscale ? rowscale[gr + r] : 1.f;
            #pragma unroll
            for (int nt = 0; nt < 4; ++nt) {
                int gc = n0 + wn * 64 + nt * 16 + l16;
                C[(size_t)(gr + r) * N + gc] = sc * fmaxf(acc[mt][nt][r] + bias[gc], 0.f);
            }
        }
    }
}

// ---------------- pooling ----------------
#define POOL_CHUNK 32
__global__ __launch_bounds__(256) void pool_kernel(const float* __restrict__ h,
                                                   const int* __restrict__ batch,
                                                   float* __restrict__ pool_sum) {
    int f = threadIdx.x;
    int start = blockIdx.x * POOL_CHUNK;
    int end = start + POOL_CHUNK; end = end < N_NODES ? end : N_NODES;
    if (start >= N_NODES) return;
    int gcur = batch[start];
    float acc = 0.f;
    for (int i = start; i < end; ++i) {
        int g = batch[i];
        if (g != gcur) { atomicAdd(&pool_sum[gcur * HID + f], acc); acc = 0.f; gcur = g; }
        acc += h[(size_t)i * HID + f];
    }
    atomicAdd(&pool_sum[gcur * HID + f], acc);
}

__device__ int lb_int(const int* __restrict__ a, int n, int v) {
    int lo = 0, hi = n;
    while (lo < hi) {
        int mid = (lo + hi) >> 1;
        if (a[mid] < v) lo = mid + 1; else hi = mid;
    }
    return lo;
}

__global__ void final_linear_kernel(const float* __restrict__ pool_sum,
                                    const int* __restrict__ batch,
                                    const float* __restrict__ Wlin,
                                    const float* __restrict__ blin,
                                    float* __restrict__ out) {
    int idx = blockIdx.x * blockDim.x + threadIdx.x;
    if (idx >= N_GRAPHS * OUT_F) return;
    int g = idx / OUT_F, o = idx % OUT_F;
    int lo = lb_int(batch, N_NODES, g);
    int hi = lb_int(batch, N_NODES, g + 1);
    float cinv = 1.f / fmaxf((float)(hi - lo), 1.f);
    float s = blin[o];
    for (int k = 0; k < HID; ++k) s += (pool_sum[g * HID + k] * cinv) * Wlin[k * OUT_F + o];
    out[idx] = s;
}

// ---------------- launch ----------------
static inline size_t align_up(size_t x, size_t a) { return (x + a - 1) & ~(a - 1); }

extern "C" void kernel_launch(void* const* d_in, const int* in_sizes, int n_in,
                              void* d_out, int out_size, void* d_ws, size_t ws_size,
                              hipStream_t stream) {
    const float* x     = (const float*)d_in[0];
    const int*   elist = (const int*)d_in[1];   // [2, E]
    const int*   batch = (const int*)d_in[2];
    const float* W1    = (const float*)d_in[3];
    const float* b1    = (const float*)d_in[4];
    const float* Wm    = (const float*)d_in[5];
    const float* bm    = (const float*)d_in[6];
    const float* Wlin  = (const float*)d_in[7];
    const float* blin  = (const float*)d_in[8];
    float* outp = (float*)d_out;

    const int* srcA = elist;
    const int* dstA = elist + N_EDGES;

    char* ws = (char*)d_ws;
    size_t off = 0;
    float* h      = (float*)(ws + off); off = align_up(off + sizeof(float) * N_NODES * HID, 1024);
    float* xs     = (float*)(ws + off); off = align_up(off + sizeof(float) * N_NODES * F_IN, 1024);
    u16*   g_hi   = (u16*)(ws + off);   off = align_up(off + sizeof(u16) * N_NODES * HID, 1024);
    u16*   g_lo   = (u16*)(ws + off);   off = align_up(off + sizeof(u16) * N_NODES * HID, 1024);
    u16*   W1T_h  = (u16*)(ws + off);   off = align_up(off + sizeof(u16) * F_IN * HID, 1024);
    u16*   W1T_l  = (u16*)(ws + off);   off = align_up(off + sizeof(u16) * F_IN * HID, 1024);
    u16*   WmT_h  = (u16*)(ws + off);   off = align_up(off + sizeof(u16) * (N_LAYERS - 1) * HID * HID, 1024);
    u16*   WmT_l  = (u16*)(ws + off);   off = align_up(off + sizeof(u16) * (N_LAYERS - 1) * HID * HID, 1024);
    int*   cursor = (int*)(ws + off);   off = align_up(off + sizeof(int) * N_NODES, 1024);
    float* dinv   = (float*)(ws + off); off = align_up(off + sizeof(float) * N_NODES, 1024);
    u16*   ell_col = (u16*)(ws + off);  off = align_up(off + sizeof(u16) * N_NODES * ELLCAP, 1024);
    float* pool_sum = (float*)(ws + off); off = align_up(off + sizeof(float) * N_GRAPHS * HID, 1024);

    hipMemsetAsync(cursor, 0, sizeof(int) * N_NODES, stream);
    hipMemsetAsync(ell_col, 0, sizeof(u16) * N_NODES * ELLCAP, stream);  // pad slots -> node 0 (masked)
    hipMemsetAsync(pool_sum, 0, sizeof(float) * N_GRAPHS * HID, stream);

    fill_ell_kernel<<<(N_EDGES + 255) / 256, 256, 0, stream>>>(srcA, dstA, cursor, ell_col, N_EDGES);
    dinv_kernel<<<(N_NODES + 255) / 256, 256, 0, stream>>>(cursor, dinv, N_NODES);
    prescale_x_kernel<<<(N_NODES * F_IN + 255) / 256, 256, 0, stream>>>(x, dinv, xs, N_NODES * F_IN);

    transpose_split_tiled<<<dim3((F_IN / 32) * (HID / 32), 1), 256, 0, stream>>>(W1, W1T_h, W1T_l, F_IN, HID);
    transpose_split_tiled<<<dim3((HID / 32) * (HID / 32), N_LAYERS - 1), 256, 0, stream>>>(Wm, WmT_h, WmT_l, HID, HID);

    const int n_row_tiles = (N_NODES + 127) / 128;            // 157
    const int ggrid = ((n_row_tiles + 7) / 8) * 8 * NCOLT;    // 320 (holes guarded in-kernel)
    // layer 1: g = agg(xs) [K=128]; h' = dinv * relu(g @ W1 + b1)
    agg_fsplit<F_IN><<<(N_NODES / 32) * (F_IN / 32), 256, 0, stream>>>(xs, ell_col, cursor, dinv, g_hi, g_lo);
    gemm_bias_relu<<<ggrid, 256, 0, stream>>>(g_hi, g_lo, W1T_h, W1T_l, b1, dinv, h, N_NODES, F_IN, HID);
    // middle layers: g = agg(h'); h' = dinv * relu(g @ W + b)  (last: unscaled for pooling)
    for (int l = 0; l < N_LAYERS - 1; ++l) {
        agg_fsplit<HID><<<(N_NODES / 32) * (HID / 32), 256, 0, stream>>>(h, ell_col, cursor, dinv, g_hi, g_lo);
        const float* rs = (l == N_LAYERS - 2) ? nullptr : dinv;
        gemm_bias_relu<<<ggrid, 256, 0, stream>>>(g_hi, g_lo, WmT_h + (size_t)l * HID * HID,
                                                  WmT_l + (size_t)l * HID * HID,
                                                  bm + (size_t)l * HID, rs, h, N_NODES, HID, HID);
    }
    pool_kernel<<<(N_NODES + POOL_CHUNK - 1) / POOL_CHUNK, 256, 0, stream>>>(h, batch, pool_sum);
    final_linear_kernel<<<2, 256, 0, stream>>>(pool_sum, batch, Wlin, blin, outp);
}

// Round 12
// 1481.089 us; speedup vs baseline: 1.3985x; 1.2441x over previous
//
#include <hip/hip_runtime.h>

typedef unsigned short u16;
typedef unsigned int u32;
typedef __attribute__((ext_vector_type(8))) short bf16x8;   // 8 bf16 = 4 VGPRs
typedef __attribute__((ext_vector_type(4))) float f32x4;
typedef __attribute__((ext_vector_type(4))) u16 u16x4;
typedef __attribute__((ext_vector_type(8))) u16 u16x8;

#define N_NODES 20000
#define N_EDGES 320000
#define F_IN 128
#define HID 256
#define OUT_F 32
#define N_LAYERS 30
#define N_GRAPHS 16
#define ELLCAP 64

// ---------------- bf16 split helpers ----------------
__device__ __forceinline__ u16 f32_to_bf16(float f) {
    u32 u = __float_as_uint(f);
    u32 r = (u + 0x7FFFu + ((u >> 16) & 1u)) >> 16;   // round-to-nearest-even
    return (u16)r;
}
__device__ __forceinline__ float bf16_to_f32(u16 h) {
    return __uint_as_float(((u32)h) << 16);
}

__device__ __forceinline__ void gl_lds16(const u16* g, u16* l) {
    __builtin_amdgcn_global_load_lds((const u32*)g, (u32*)l, 16, 0, 0);
}

// ---------------- graph build ----------------
// fill_ell also produces the degree: cursor's final value == in-degree at dst.
// ell_col is pre-zeroed; unfilled slots stay 0 (node 0: valid, masked off in agg).
__global__ void fill_ell_kernel(const int* __restrict__ src, const int* __restrict__ dst,
                                int* __restrict__ cursor, u16* __restrict__ ell_col, int E) {
    int e = blockIdx.x * blockDim.x + threadIdx.x;
    if (e >= E) return;
    int s = src[e], d = dst[e];
    int slot = atomicAdd(&cursor[d], 1);
    if (slot < ELLCAP) ell_col[d * ELLCAP + slot] = (u16)s;
}

__global__ void dinv_kernel(const int* __restrict__ cnt, float* __restrict__ dinv, int n) {
    int i = blockIdx.x * blockDim.x + threadIdx.x;
    if (i < n) dinv[i] = rsqrtf((float)(cnt[i] + 1));  // +1 self loop
}

// x' = dinv ⊙ x  (pre-scaled gather source for layer 1)
__global__ void prescale_x_kernel(const float* __restrict__ x, const float* __restrict__ dinv,
                                  float* __restrict__ xs, int total) {
    int i = blockIdx.x * 256 + threadIdx.x;
    if (i < total) xs[i] = x[i] * dinv[i >> 7];   // F_IN = 128
}

// ---------------- weight split+transpose (LDS-tiled, coalesced writes) ----------------
// W [L][K][N] -> Th/Tl [L][N][K]; 32x32 tiles.
__global__ __launch_bounds__(256) void transpose_split_tiled(const float* __restrict__ W,
                                                             u16* __restrict__ Th, u16* __restrict__ Tl,
                                                             int K, int N) {
    __shared__ float tile[32][33];
    const int l = blockIdx.y;
    const int ntn = N >> 5;
    const int kt = blockIdx.x / ntn, ntile = blockIdx.x % ntn;
    const float* Wl = W + (size_t)l * K * N;
    u16* Thl = Th + (size_t)l * K * N;
    u16* Tll = Tl + (size_t)l * K * N;
    const int r8 = threadIdx.x >> 5, c = threadIdx.x & 31;
    #pragma unroll
    for (int rr = 0; rr < 4; ++rr) {
        int r = rr * 8 + r8;
        tile[r][c] = Wl[(size_t)(kt * 32 + r) * N + ntile * 32 + c];
    }
    __syncthreads();
    #pragma unroll
    for (int rr = 0; rr < 4; ++rr) {
        int n = rr * 8 + r8;                 // transposed row (N dim)
        float v = tile[c][n];                // W[k=kt*32+c][n]
        u16 hb = f32_to_bf16(v);
        u16 lb = f32_to_bf16(v - bf16_to_f32(hb));
        size_t o = (size_t)(ntile * 32 + n) * K + kt * 32 + c;
        Thl[o] = hb;
        Tll[o] = lb;
    }
}

// ---------------- feature-split aggregation ----------------
// g[d] = dinv[d] * (sum_{s in N(d)} hs[s] + hs[d]), hs pre-scaled by dinv.
// Block = 32 nodes x one 32-feature chunk; fc = blockIdx & (CHUNKS-1): round-robin
// block->XCD dispatch pins one feature slice (2.56 MB) per XCD L2.
// 8 lanes/node, f32x4/lane. Full 8-batches only (zero-padded ELL, masked final adds)
// -> one waitcnt per batch, no serial-latency tail. Depth-2 software pipeline.
template <int F>
__global__ __launch_bounds__(256) void agg_fsplit(const float* __restrict__ hs,
                                                  const u16* __restrict__ ell_col,
                                                  const int* __restrict__ cnt,
                                                  const float* __restrict__ dinv,
                                                  u16* __restrict__ ghi, u16* __restrict__ glo) {
    constexpr int CHUNKS = F / 32;
    __shared__ u16 cols[32 * ELLCAP];
    const int blk = blockIdx.x;
    const int fc = blk & (CHUNKS - 1);
    const int grp = blk / CHUNKS;
    const int node0 = grp * 32;
    const int tid = threadIdx.x;
    *(u16x8*)&cols[tid * 8] = *(const u16x8*)&ell_col[(size_t)node0 * ELLCAP + tid * 8];
    const int g = tid >> 3, sub = tid & 7;
    const int node = node0 + g;
    const int f = fc * 32 + sub * 4;
    int c = cnt[node]; c = c < ELLCAP ? c : ELLCAP;
    const float dd = dinv[node];
    f32x4 acc = *(const f32x4*)(hs + (size_t)node * F + f);   // self loop (pre-scaled)
    __syncthreads();
    const u16* cl = &cols[g * ELLCAP];
    const int nb = (c + 7) >> 3;   // number of 8-batches (last one masked)
    if (nb > 0) {
        const f32x4 zero = {0.f, 0.f, 0.f, 0.f};
        f32x4 vbuf[8];
        u16x8 cc = *(const u16x8*)&cl[0];
        #pragma unroll
        for (int j = 0; j < 8; ++j) vbuf[j] = *(const f32x4*)(hs + (size_t)cc[j] * F + f);
        int base = 0;
        for (int b = 1; b < nb; ++b) {
            u16x8 cn = *(const u16x8*)&cl[b * 8];
            f32x4 vn[8];
            #pragma unroll
            for (int j = 0; j < 8; ++j) vn[j] = *(const f32x4*)(hs + (size_t)cn[j] * F + f);
            #pragma unroll
            for (int j = 0; j < 8; ++j) acc += vbuf[j];   // non-final batches are full
            base += 8;
            #pragma unroll
            for (int j = 0; j < 8; ++j) vbuf[j] = vn[j];
        }
        #pragma unroll
        for (int j = 0; j < 8; ++j) acc += (base + j < c) ? vbuf[j] : zero;  // masked final batch
    }
    u16x4 vh, vl;
    #pragma unroll
    for (int i = 0; i < 4; ++i) {
        float v = acc[i] * dd;
        u16 hb = f32_to_bf16(v);
        vh[i] = hb;
        vl[i] = f32_to_bf16(v - bf16_to_f32(hb));
    }
    *(u16x4*)(ghi + (size_t)node * F + f) = vh;
    *(u16x4*)(glo + (size_t)node * F + f) = vl;
}

// ---------------- split-bf16 MFMA GEMM + bias + relu (+ optional row scale) ----------------
// C[M][N] = rowscale[m] * relu((Ah+Al)[M][K] @ (Bh+Bl)^T + bias), B transposed [N][K].
// Tile: 128(M) x 128(N) x 64(K). 256 threads = 4 waves (2x2), wave = 64m x 64n (4x4 frags).
// Both A and B staged via global_load_lds (64 KB LDS, 2 blocks/CU) — the R5-proven shape.
// XCD-swizzled 1D grid: row-tile's 2 n-tiles share id%8 -> A re-stage hits home-XCD L2.
// Per kk: 16 ds_read_b128 (192 cyc) vs 48 MFMA (233 cyc) -> MFMA-bound inner loop.
#define NCOLT 2   // N/128
__global__ __launch_bounds__(256, 2) void gemm_bias_relu(const u16* __restrict__ Ah, const u16* __restrict__ Al,
                                                         const u16* __restrict__ Bh, const u16* __restrict__ Bl,
                                                         const float* __restrict__ bias,
                                                         const float* __restrict__ rowscale,
                                                         float* __restrict__ C, int M, int K, int N) {
    __shared__ __align__(16) u16 As_h[128 * 64];
    __shared__ __align__(16) u16 As_l[128 * 64];
    __shared__ __align__(16) u16 Bs_h[128 * 64];
    __shared__ __align__(16) u16 Bs_l[128 * 64];
    const int bid = blockIdx.x;
    const int slot = bid & 7;
    const int j = bid >> 3;
    const int ncol = j & (NCOLT - 1);
    const int rowhi = j / NCOLT;
    const int row_tile = rowhi * 8 + slot;
    const int row0 = row_tile * 128;
    if (row0 >= M) return;
    const int n0 = ncol * 128;
    const int tid = threadIdx.x;
    const int wave = tid >> 6, lane = tid & 63;
    const int wm = wave >> 1, wn = wave & 1;
    const int lr = lane >> 3;   // row within 8-row staging group
    const int lc = lane & 7;    // 16B-chunk position within row
    f32x4 acc[4][4] = {};

    for (int k0 = 0; k0 < K; k0 += 64) {
        // stage A hi/lo: 128 rows x 64 k, XOR-swizzled chunks
        #pragma unroll
        for (int q = 0; q < 4; ++q) {
            int rl = (wave * 4 + q) * 8 + lr;
            int ra = row0 + rl; ra = ra < M ? ra : (M - 1);   // clamp tail (rows >= M unused)
            int cg = (lc ^ (rl & 7)) << 3;
            gl_lds16(Ah + (size_t)ra * K + k0 + cg, &As_h[(wave * 4 + q) * 512]);
            gl_lds16(Al + (size_t)ra * K + k0 + cg, &As_l[(wave * 4 + q) * 512]);
        }
        // stage B^T hi/lo: 128 n-rows x 64 k
        #pragma unroll
        for (int q = 0; q < 4; ++q) {
            int rl = (wave * 4 + q) * 8 + lr;
            int ng = n0 + rl;
            int cg = (lc ^ (rl & 7)) << 3;
            gl_lds16(Bh + (size_t)ng * K + k0 + cg, &Bs_h[(wave * 4 + q) * 512]);
            gl_lds16(Bl + (size_t)ng * K + k0 + cg, &Bs_l[(wave * 4 + q) * 512]);
        }
        __syncthreads();
        #pragma unroll
        for (int kk = 0; kk < 2; ++kk) {
            const int cidx = kk * 4 + (lane >> 4);
            bf16x8 bhf[4], blf[4];
            #pragma unroll
            for (int nt = 0; nt < 4; ++nt) {
                int nl = wn * 64 + nt * 16 + (lane & 15);
                int off = nl * 64 + ((cidx ^ (nl & 7)) << 3);
                bhf[nt] = *(const bf16x8*)&Bs_h[off];
                blf[nt] = *(const bf16x8*)&Bs_l[off];
            }
            #pragma unroll
            for (int mt = 0; mt < 4; ++mt) {
                int ml = wm * 64 + mt * 16 + (lane & 15);
                int off = ml * 64 + ((cidx ^ (ml & 7)) << 3);
                bf16x8 ah = *(const bf16x8*)&As_h[off];
                bf16x8 al = *(const bf16x8*)&As_l[off];
                #pragma unroll
                for (int nt = 0; nt < 4; ++nt) {
                    acc[mt][nt] = __builtin_amdgcn_mfma_f32_16x16x32_bf16(ah, bhf[nt], acc[mt][nt], 0, 0, 0);
                    acc[mt][nt] = __builtin_amdgcn_mfma_f32_16x16x32_bf16(ah, blf[nt], acc[mt][nt], 0, 0, 0);
                    acc[mt][nt] = __builtin_amdgcn_mfma_f32_16x16x32_bf16(al, bhf[nt], acc[mt][nt], 0, 0, 0);
                }
            }
        }
        __syncthreads();
    }
    // epilogue: bias + relu (+ dinv row scale); C/D layout col=lane&15, row=(lane>>4)*4+r
    #pragma unroll
    for (int mt = 0; mt < 4; ++mt) {
        int gr = row0 + wm * 64 + mt * 16 + ((lane >> 4) << 2);
        #pragma unroll
        for (int r = 0; r < 4; ++r) {
            if (gr + r >= M) continue;
            float sc = rowscale ? rowscale[gr + r] : 1.f;
            #pragma unroll
            for (int nt = 0; nt < 4; ++nt) {
                int gc = n0 + wn * 64 + nt * 16 + (lane & 15);
                C[(size_t)(gr + r) * N + gc] = sc * fmaxf(acc[mt][nt][r] + bias[gc], 0.f);
            }
        }
    }
}

// ---------------- pooling ----------------
#define POOL_CHUNK 32
__global__ __launch_bounds__(256) void pool_kernel(const float* __restrict__ h,
                                                   const int* __restrict__ batch,
                                                   float* __restrict__ pool_sum) {
    int f = threadIdx.x;
    int start = blockIdx.x * POOL_CHUNK;
    int end = start + POOL_CHUNK; end = end < N_NODES ? end : N_NODES;
    if (start >= N_NODES) return;
    int gcur = batch[start];
    float acc = 0.f;
    for (int i = start; i < end; ++i) {
        int g = batch[i];
        if (g != gcur) { atomicAdd(&pool_sum[gcur * HID + f], acc); acc = 0.f; gcur = g; }
        acc += h[(size_t)i * HID + f];
    }
    atomicAdd(&pool_sum[gcur * HID + f], acc);
}

__device__ int lb_int(const int* __restrict__ a, int n, int v) {
    int lo = 0, hi = n;
    while (lo < hi) {
        int mid = (lo + hi) >> 1;
        if (a[mid] < v) lo = mid + 1; else hi = mid;
    }
    return lo;
}

__global__ void final_linear_kernel(const float* __restrict__ pool_sum,
                                    const int* __restrict__ batch,
                                    const float* __restrict__ Wlin,
                                    const float* __restrict__ blin,
                                    float* __restrict__ out) {
    int idx = blockIdx.x * blockDim.x + threadIdx.x;
    if (idx >= N_GRAPHS * OUT_F) return;
    int g = idx / OUT_F, o = idx % OUT_F;
    int lo = lb_int(batch, N_NODES, g);
    int hi = lb_int(batch, N_NODES, g + 1);
    float cinv = 1.f / fmaxf((float)(hi - lo), 1.f);
    float s = blin[o];
    for (int k = 0; k < HID; ++k) s += (pool_sum[g * HID + k] * cinv) * Wlin[k * OUT_F + o];
    out[idx] = s;
}

// ---------------- launch ----------------
static inline size_t align_up(size_t x, size_t a) { return (x + a - 1) & ~(a - 1); }

extern "C" void kernel_launch(void* const* d_in, const int* in_sizes, int n_in,
                              void* d_out, int out_size, void* d_ws, size_t ws_size,
                              hipStream_t stream) {
    const float* x     = (const float*)d_in[0];
    const int*   elist = (const int*)d_in[1];   // [2, E]
    const int*   batch = (const int*)d_in[2];
    const float* W1    = (const float*)d_in[3];
    const float* b1    = (const float*)d_in[4];
    const float* Wm    = (const float*)d_in[5];
    const float* bm    = (const float*)d_in[6];
    const float* Wlin  = (const float*)d_in[7];
    const float* blin  = (const float*)d_in[8];
    float* outp = (float*)d_out;

    const int* srcA = elist;
    const int* dstA = elist + N_EDGES;

    char* ws = (char*)d_ws;
    size_t off = 0;
    float* h      = (float*)(ws + off); off = align_up(off + sizeof(float) * N_NODES * HID, 1024);
    float* xs     = (float*)(ws + off); off = align_up(off + sizeof(float) * N_NODES * F_IN, 1024);
    u16*   g_hi   = (u16*)(ws + off);   off = align_up(off + sizeof(u16) * N_NODES * HID, 1024);
    u16*   g_lo   = (u16*)(ws + off);   off = align_up(off + sizeof(u16) * N_NODES * HID, 1024);
    u16*   W1T_h  = (u16*)(ws + off);   off = align_up(off + sizeof(u16) * F_IN * HID, 1024);
    u16*   W1T_l  = (u16*)(ws + off);   off = align_up(off + sizeof(u16) * F_IN * HID, 1024);
    u16*   WmT_h  = (u16*)(ws + off);   off = align_up(off + sizeof(u16) * (N_LAYERS - 1) * HID * HID, 1024);
    u16*   WmT_l  = (u16*)(ws + off);   off = align_up(off + sizeof(u16) * (N_LAYERS - 1) * HID * HID, 1024);
    int*   cursor = (int*)(ws + off);   off = align_up(off + sizeof(int) * N_NODES, 1024);
    float* dinv   = (float*)(ws + off); off = align_up(off + sizeof(float) * N_NODES, 1024);
    u16*   ell_col = (u16*)(ws + off);  off = align_up(off + sizeof(u16) * N_NODES * ELLCAP, 1024);
    float* pool_sum = (float*)(ws + off); off = align_up(off + sizeof(float) * N_GRAPHS * HID, 1024);

    hipMemsetAsync(cursor, 0, sizeof(int) * N_NODES, stream);
    hipMemsetAsync(ell_col, 0, sizeof(u16) * N_NODES * ELLCAP, stream);  // pad slots -> node 0 (masked)
    hipMemsetAsync(pool_sum, 0, sizeof(float) * N_GRAPHS * HID, stream);

    fill_ell_kernel<<<(N_EDGES + 255) / 256, 256, 0, stream>>>(srcA, dstA, cursor, ell_col, N_EDGES);
    dinv_kernel<<<(N_NODES + 255) / 256, 256, 0, stream>>>(cursor, dinv, N_NODES);
    prescale_x_kernel<<<(N_NODES * F_IN + 255) / 256, 256, 0, stream>>>(x, dinv, xs, N_NODES * F_IN);

    transpose_split_tiled<<<dim3((F_IN / 32) * (HID / 32), 1), 256, 0, stream>>>(W1, W1T_h, W1T_l, F_IN, HID);
    transpose_split_tiled<<<dim3((HID / 32) * (HID / 32), N_LAYERS - 1), 256, 0, stream>>>(Wm, WmT_h, WmT_l, HID, HID);

    const int n_row_tiles = (N_NODES + 127) / 128;            // 157
    const int ggrid = ((n_row_tiles + 7) / 8) * 8 * NCOLT;    // 320 (holes guarded in-kernel)
    // layer 1: g = agg(xs) [K=128]; h' = dinv * relu(g @ W1 + b1)
    agg_fsplit<F_IN><<<(N_NODES / 32) * (F_IN / 32), 256, 0, stream>>>(xs, ell_col, cursor, dinv, g_hi, g_lo);
    gemm_bias_relu<<<ggrid, 256, 0, stream>>>(g_hi, g_lo, W1T_h, W1T_l, b1, dinv, h, N_NODES, F_IN, HID);
    // middle layers: g = agg(h'); h' = dinv * relu(g @ W + b)  (last: unscaled for pooling)
    for (int l = 0; l < N_LAYERS - 1; ++l) {
        agg_fsplit<HID><<<(N_NODES / 32) * (HID / 32), 256, 0, stream>>>(h, ell_col, cursor, dinv, g_hi, g_lo);
        const float* rs = (l == N_LAYERS - 2) ? nullptr : dinv;
        gemm_bias_relu<<<ggrid, 256, 0, stream>>>(g_hi, g_lo, WmT_h + (size_t)l * HID * HID,
                                                  WmT_l + (size_t)l * HID * HID,
                                                  bm + (size_t)l * HID, rs, h, N_NODES, HID, HID);
    }
    pool_kernel<<<(N_NODES + POOL_CHUNK - 1) / POOL_CHUNK, 256, 0, stream>>>(h, batch, pool_sum);
    final_linear_kernel<<<2, 256, 0, stream>>>(pool_sum, batch, Wlin, blin, outp);
}

// Round 13
// 1422.020 us; speedup vs baseline: 1.4566x; 1.0415x over previous
//
#include <hip/hip_runtime.h>

typedef unsigned short u16;
typedef unsigned int u32;
typedef __attribute__((ext_vector_type(8))) short bf16x8;   // 8 bf16 = 4 VGPRs
typedef __attribute__((ext_vector_type(4))) float f32x4;
typedef __attribute__((ext_vector_type(4))) u16 u16x4;
typedef __attribute__((ext_vector_type(8))) u16 u16x8;

#define N_NODES 20000
#define N_EDGES 320000
#define F_IN 128
#define HID 256
#define OUT_F 32
#define N_LAYERS 30
#define N_GRAPHS 16
#define ELLCAP 64

// ---------------- bf16 split helpers ----------------
__device__ __forceinline__ u16 f32_to_bf16(float f) {
    u32 u = __float_as_uint(f);
    u32 r = (u + 0x7FFFu + ((u >> 16) & 1u)) >> 16;   // round-to-nearest-even
    return (u16)r;
}
__device__ __forceinline__ float bf16_to_f32(u16 h) {
    return __uint_as_float(((u32)h) << 16);
}

__device__ __forceinline__ void gl_lds16(const u16* g, u16* l) {
    __builtin_amdgcn_global_load_lds((const u32*)g, (u32*)l, 16, 0, 0);
}

// ---------------- graph build ----------------
// fill_ell also produces the degree: cursor's final value == in-degree at dst.
// ell_col is pre-zeroed; unfilled slots stay 0 (node 0: valid, masked off in agg).
__global__ void fill_ell_kernel(const int* __restrict__ src, const int* __restrict__ dst,
                                int* __restrict__ cursor, u16* __restrict__ ell_col, int E) {
    int e = blockIdx.x * blockDim.x + threadIdx.x;
    if (e >= E) return;
    int s = src[e], d = dst[e];
    int slot = atomicAdd(&cursor[d], 1);
    if (slot < ELLCAP) ell_col[d * ELLCAP + slot] = (u16)s;
}

__global__ void dinv_kernel(const int* __restrict__ cnt, float* __restrict__ dinv, int n) {
    int i = blockIdx.x * blockDim.x + threadIdx.x;
    if (i < n) dinv[i] = rsqrtf((float)(cnt[i] + 1));  // +1 self loop
}

// x' = dinv ⊙ x, dinv computed inline from degree (no dependency on dinv_kernel)
__global__ void prescale_x_kernel(const float* __restrict__ x, const int* __restrict__ cnt,
                                  float* __restrict__ xs, int total) {
    int i = blockIdx.x * 256 + threadIdx.x;
    if (i < total) xs[i] = x[i] * rsqrtf((float)(cnt[i >> 7] + 1));   // F_IN = 128
}

// ---------------- weight split+transpose (LDS-tiled, coalesced writes) ----------------
// W [L][K][N] -> Th/Tl [L][N][K]; 32x32 tiles.
__global__ __launch_bounds__(256) void transpose_split_tiled(const float* __restrict__ W,
                                                             u16* __restrict__ Th, u16* __restrict__ Tl,
                                                             int K, int N) {
    __shared__ float tile[32][33];
    const int l = blockIdx.y;
    const int ntn = N >> 5;
    const int kt = blockIdx.x / ntn, ntile = blockIdx.x % ntn;
    const float* Wl = W + (size_t)l * K * N;
    u16* Thl = Th + (size_t)l * K * N;
    u16* Tll = Tl + (size_t)l * K * N;
    const int r8 = threadIdx.x >> 5, c = threadIdx.x & 31;
    #pragma unroll
    for (int rr = 0; rr < 4; ++rr) {
        int r = rr * 8 + r8;
        tile[r][c] = Wl[(size_t)(kt * 32 + r) * N + ntile * 32 + c];
    }
    __syncthreads();
    #pragma unroll
    for (int rr = 0; rr < 4; ++rr) {
        int n = rr * 8 + r8;                 // transposed row (N dim)
        float v = tile[c][n];                // W[k=kt*32+c][n]
        u16 hb = f32_to_bf16(v);
        u16 lb = f32_to_bf16(v - bf16_to_f32(hb));
        size_t o = (size_t)(ntile * 32 + n) * K + kt * 32 + c;
        Thl[o] = hb;
        Tll[o] = lb;
    }
}

// ---------------- feature-split aggregation ----------------
// g[d] = dinv[d] * (sum_{s in N(d)} hs[s] + hs[d]), hs pre-scaled by dinv.
// Block = 32 nodes x one 32-feature chunk; fc = blockIdx & (CHUNKS-1): round-robin
// block->XCD dispatch pins one feature slice (2.56 MB) per XCD L2.
// 8 lanes/node, f32x4/lane. Full 8-batches only (zero-padded ELL, masked final adds)
// -> one waitcnt per batch, no serial-latency tail. Depth-2 software pipeline.
// NOTE (R12 analysis): this kernel runs at the per-XCD L2 request-rate roofline
// (~340K line-touches/XCD/layer); byte-level re-chunking cannot reduce it.
template <int F>
__global__ __launch_bounds__(256) void agg_fsplit(const float* __restrict__ hs,
                                                  const u16* __restrict__ ell_col,
                                                  const int* __restrict__ cnt,
                                                  const float* __restrict__ dinv,
                                                  u16* __restrict__ ghi, u16* __restrict__ glo) {
    constexpr int CHUNKS = F / 32;
    __shared__ u16 cols[32 * ELLCAP];
    const int blk = blockIdx.x;
    const int fc = blk & (CHUNKS - 1);
    const int grp = blk / CHUNKS;
    const int node0 = grp * 32;
    const int tid = threadIdx.x;
    *(u16x8*)&cols[tid * 8] = *(const u16x8*)&ell_col[(size_t)node0 * ELLCAP + tid * 8];
    const int g = tid >> 3, sub = tid & 7;
    const int node = node0 + g;
    const int f = fc * 32 + sub * 4;
    int c = cnt[node]; c = c < ELLCAP ? c : ELLCAP;
    const float dd = dinv[node];
    f32x4 acc = *(const f32x4*)(hs + (size_t)node * F + f);   // self loop (pre-scaled)
    __syncthreads();
    const u16* cl = &cols[g * ELLCAP];
    const int nb = (c + 7) >> 3;   // number of 8-batches (last one masked)
    if (nb > 0) {
        const f32x4 zero = {0.f, 0.f, 0.f, 0.f};
        f32x4 vbuf[8];
        u16x8 cc = *(const u16x8*)&cl[0];
        #pragma unroll
        for (int j = 0; j < 8; ++j) vbuf[j] = *(const f32x4*)(hs + (size_t)cc[j] * F + f);
        int base = 0;
        for (int b = 1; b < nb; ++b) {
            u16x8 cn = *(const u16x8*)&cl[b * 8];
            f32x4 vn[8];
            #pragma unroll
            for (int j = 0; j < 8; ++j) vn[j] = *(const f32x4*)(hs + (size_t)cn[j] * F + f);
            #pragma unroll
            for (int j = 0; j < 8; ++j) acc += vbuf[j];   // non-final batches are full
            base += 8;
            #pragma unroll
            for (int j = 0; j < 8; ++j) vbuf[j] = vn[j];
        }
        #pragma unroll
        for (int j = 0; j < 8; ++j) acc += (base + j < c) ? vbuf[j] : zero;  // masked final batch
    }
    u16x4 vh, vl;
    #pragma unroll
    for (int i = 0; i < 4; ++i) {
        float v = acc[i] * dd;
        u16 hb = f32_to_bf16(v);
        vh[i] = hb;
        vl[i] = f32_to_bf16(v - bf16_to_f32(hb));
    }
    *(u16x4*)(ghi + (size_t)node * F + f) = vh;
    *(u16x4*)(glo + (size_t)node * F + f) = vl;
}

// ---------------- split-bf16 MFMA GEMM + bias + relu (+ optional row scale) ----------------
// C[M][N] = rowscale[m] * relu((Ah+Al)[M][K] @ (Bh+Bl)^T + bias), B transposed [N][K].
// Tile: 128(M) x 64(N) x 64(K), 3 blocks/CU — the best-measured configuration (R9).
// XCD-swizzled 1D grid: id = 8*(rowhi*NCOLT + ncol) + slot, row_tile = rowhi*8 + slot.
// All NCOLT n-tiles of a row share id%8 -> same XCD -> A row-tile re-read from L2.
#define NCOLT 4   // N/64 = 256/64
__global__ __launch_bounds__(256, 3) void gemm_bias_relu(const u16* __restrict__ Ah, const u16* __restrict__ Al,
                                                         const u16* __restrict__ Bh, const u16* __restrict__ Bl,
                                                         const float* __restrict__ bias,
                                                         const float* __restrict__ rowscale,
                                                         float* __restrict__ C, int M, int K, int N) {
    __shared__ __align__(16) u16 As_h[128 * 64];
    __shared__ __align__(16) u16 As_l[128 * 64];
    __shared__ __align__(16) u16 Bs_h[64 * 64];
    __shared__ __align__(16) u16 Bs_l[64 * 64];
    const int bid = blockIdx.x;
    const int slot = bid & 7;
    const int j = bid >> 3;
    const int ncol = j & (NCOLT - 1);
    const int rowhi = j / NCOLT;
    const int row_tile = rowhi * 8 + slot;
    const int row0 = row_tile * 128;
    if (row0 >= M) return;
    const int n0 = ncol * 64;
    const int tid = threadIdx.x;
    const int wave = tid >> 6, lane = tid & 63;
    const int wm = wave >> 1, wn = wave & 1;
    const int lr = lane >> 3;   // row within 8-row staging group
    const int lc = lane & 7;    // 16B-chunk position within row
    f32x4 acc[4][2] = {};

    for (int k0 = 0; k0 < K; k0 += 64) {
        // stage A hi/lo: 128 rows x 64 k, XOR-swizzled chunks
        #pragma unroll
        for (int q = 0; q < 4; ++q) {
            int rl = (wave * 4 + q) * 8 + lr;
            int ra = row0 + rl; ra = ra < M ? ra : (M - 1);   // clamp tail (rows >= M unused)
            int cg = (lc ^ (rl & 7)) << 3;
            gl_lds16(Ah + (size_t)ra * K + k0 + cg, &As_h[(wave * 4 + q) * 512]);
            gl_lds16(Al + (size_t)ra * K + k0 + cg, &As_l[(wave * 4 + q) * 512]);
        }
        // stage B^T hi/lo: 64 n-rows x 64 k
        #pragma unroll
        for (int q = 0; q < 2; ++q) {
            int rl = (wave * 2 + q) * 8 + lr;
            int ng = n0 + rl;
            int cg = (lc ^ (rl & 7)) << 3;
            gl_lds16(Bh + (size_t)ng * K + k0 + cg, &Bs_h[(wave * 2 + q) * 512]);
            gl_lds16(Bl + (size_t)ng * K + k0 + cg, &Bs_l[(wave * 2 + q) * 512]);
        }
        __syncthreads();
        #pragma unroll
        for (int kk = 0; kk < 2; ++kk) {
            const int cidx = kk * 4 + (lane >> 4);
            bf16x8 bhf[2], blf[2];
            #pragma unroll
            for (int nt = 0; nt < 2; ++nt) {
                int nl = wn * 32 + nt * 16 + (lane & 15);
                int off = nl * 64 + ((cidx ^ (nl & 7)) << 3);
                bhf[nt] = *(const bf16x8*)&Bs_h[off];
                blf[nt] = *(const bf16x8*)&Bs_l[off];
            }
            #pragma unroll
            for (int mt = 0; mt < 4; ++mt) {
                int ml = wm * 64 + mt * 16 + (lane & 15);
                int off = ml * 64 + ((cidx ^ (ml & 7)) << 3);
                bf16x8 ah = *(const bf16x8*)&As_h[off];
                bf16x8 al = *(const bf16x8*)&As_l[off];
                #pragma unroll
                for (int nt = 0; nt < 2; ++nt) {
                    acc[mt][nt] = __builtin_amdgcn_mfma_f32_16x16x32_bf16(ah, bhf[nt], acc[mt][nt], 0, 0, 0);
                    acc[mt][nt] = __builtin_amdgcn_mfma_f32_16x16x32_bf16(ah, blf[nt], acc[mt][nt], 0, 0, 0);
                    acc[mt][nt] = __builtin_amdgcn_mfma_f32_16x16x32_bf16(al, bhf[nt], acc[mt][nt], 0, 0, 0);
                }
            }
        }
        __syncthreads();
    }
    // epilogue: bias + relu (+ dinv row scale); C/D layout col=lane&15, row=(lane>>4)*4+r
    #pragma unroll
    for (int mt = 0; mt < 4; ++mt) {
        int gr = row0 + wm * 64 + mt * 16 + ((lane >> 4) << 2);
        #pragma unroll
        for (int r = 0; r < 4; ++r) {
            if (gr + r >= M) continue;
            float sc = rowscale ? rowscale[gr + r] : 1.f;
            #pragma unroll
            for (int nt = 0; nt < 2; ++nt) {
                int gc = n0 + wn * 32 + nt * 16 + (lane & 15);
                C[(size_t)(gr + r) * N + gc] = sc * fmaxf(acc[mt][nt][r] + bias[gc], 0.f);
            }
        }
    }
}

// ---------------- pooling ----------------
#define POOL_CHUNK 32
__global__ __launch_bounds__(256) void pool_kernel(const float* __restrict__ h,
                                                   const int* __restrict__ batch,
                                                   float* __restrict__ pool_sum) {
    int f = threadIdx.x;
    int start = blockIdx.x * POOL_CHUNK;
    int end = start + POOL_CHUNK; end = end < N_NODES ? end : N_NODES;
    if (start >= N_NODES) return;
    int gcur = batch[start];
    float acc = 0.f;
    for (int i = start; i < end; ++i) {
        int g = batch[i];
        if (g != gcur) { atomicAdd(&pool_sum[gcur * HID + f], acc); acc = 0.f; gcur = g; }
        acc += h[(size_t)i * HID + f];
    }
    atomicAdd(&pool_sum[gcur * HID + f], acc);
}

__device__ int lb_int(const int* __restrict__ a, int n, int v) {
    int lo = 0, hi = n;
    while (lo < hi) {
        int mid = (lo + hi) >> 1;
        if (a[mid] < v) lo = mid + 1; else hi = mid;
    }
    return lo;
}

__global__ void final_linear_kernel(const float* __restrict__ pool_sum,
                                    const int* __restrict__ batch,
                                    const float* __restrict__ Wlin,
                                    const float* __restrict__ blin,
                                    float* __restrict__ out) {
    int idx = blockIdx.x * blockDim.x + threadIdx.x;
    if (idx >= N_GRAPHS * OUT_F) return;
    int g = idx / OUT_F, o = idx % OUT_F;
    int lo = lb_int(batch, N_NODES, g);
    int hi = lb_int(batch, N_NODES, g + 1);
    float cinv = 1.f / fmaxf((float)(hi - lo), 1.f);
    float s = blin[o];
    for (int k = 0; k < HID; ++k) s += (pool_sum[g * HID + k] * cinv) * Wlin[k * OUT_F + o];
    out[idx] = s;
}

// ---------------- launch ----------------
static inline size_t align_up(size_t x, size_t a) { return (x + a - 1) & ~(a - 1); }

extern "C" void kernel_launch(void* const* d_in, const int* in_sizes, int n_in,
                              void* d_out, int out_size, void* d_ws, size_t ws_size,
                              hipStream_t stream) {
    const float* x     = (const float*)d_in[0];
    const int*   elist = (const int*)d_in[1];   // [2, E]
    const int*   batch = (const int*)d_in[2];
    const float* W1    = (const float*)d_in[3];
    const float* b1    = (const float*)d_in[4];
    const float* Wm    = (const float*)d_in[5];
    const float* bm    = (const float*)d_in[6];
    const float* Wlin  = (const float*)d_in[7];
    const float* blin  = (const float*)d_in[8];
    float* outp = (float*)d_out;

    const int* srcA = elist;
    const int* dstA = elist + N_EDGES;

    char* ws = (char*)d_ws;
    size_t off = 0;
    float* h      = (float*)(ws + off); off = align_up(off + sizeof(float) * N_NODES * HID, 1024);
    float* xs     = (float*)(ws + off); off = align_up(off + sizeof(float) * N_NODES * F_IN, 1024);
    u16*   g_hi   = (u16*)(ws + off);   off = align_up(off + sizeof(u16) * N_NODES * HID, 1024);
    u16*   g_lo   = (u16*)(ws + off);   off = align_up(off + sizeof(u16) * N_NODES * HID, 1024);
    u16*   W1T_h  = (u16*)(ws + off);   off = align_up(off + sizeof(u16) * F_IN * HID, 1024);
    u16*   W1T_l  = (u16*)(ws + off);   off = align_up(off + sizeof(u16) * F_IN * HID, 1024);
    u16*   WmT_h  = (u16*)(ws + off);   off = align_up(off + sizeof(u16) * (N_LAYERS - 1) * HID * HID, 1024);
    u16*   WmT_l  = (u16*)(ws + off);   off = align_up(off + sizeof(u16) * (N_LAYERS - 1) * HID * HID, 1024);
    int*   cursor = (int*)(ws + off);   off = align_up(off + sizeof(int) * N_NODES, 1024);
    float* dinv   = (float*)(ws + off); off = align_up(off + sizeof(float) * N_NODES, 1024);
    u16*   ell_col = (u16*)(ws + off);  off = align_up(off + sizeof(u16) * N_NODES * ELLCAP, 1024);
    float* pool_sum = (float*)(ws + off); off = align_up(off + sizeof(float) * N_GRAPHS * HID, 1024);

    hipMemsetAsync(cursor, 0, sizeof(int) * N_NODES, stream);
    hipMemsetAsync(ell_col, 0, sizeof(u16) * N_NODES * ELLCAP, stream);  // pad slots -> node 0 (masked)
    hipMemsetAsync(pool_sum, 0, sizeof(float) * N_GRAPHS * HID, stream);

    fill_ell_kernel<<<(N_EDGES + 255) / 256, 256, 0, stream>>>(srcA, dstA, cursor, ell_col, N_EDGES);
    dinv_kernel<<<(N_NODES + 255) / 256, 256, 0, stream>>>(cursor, dinv, N_NODES);
    prescale_x_kernel<<<(N_NODES * F_IN + 255) / 256, 256, 0, stream>>>(x, cursor, xs, N_NODES * F_IN);

    transpose_split_tiled<<<dim3((F_IN / 32) * (HID / 32), 1), 256, 0, stream>>>(W1, W1T_h, W1T_l, F_IN, HID);
    transpose_split_tiled<<<dim3((HID / 32) * (HID / 32), N_LAYERS - 1), 256, 0, stream>>>(Wm, WmT_h, WmT_l, HID, HID);

    const int n_row_tiles = (N_NODES + 127) / 128;            // 157
    const int ggrid = ((n_row_tiles + 7) / 8) * 8 * NCOLT;    // 640 (holes guarded in-kernel)
    // layer 1: g = agg(xs) [K=128]; h' = dinv * relu(g @ W1 + b1)
    agg_fsplit<F_IN><<<(N_NODES / 32) * (F_IN / 32), 256, 0, stream>>>(xs, ell_col, cursor, dinv, g_hi, g_lo);
    gemm_bias_relu<<<ggrid, 256, 0, stream>>>(g_hi, g_lo, W1T_h, W1T_l, b1, dinv, h, N_NODES, F_IN, HID);
    // middle layers: g = agg(h'); h' = dinv * relu(g @ W + b)  (last: unscaled for pooling)
    for (int l = 0; l < N_LAYERS - 1; ++l) {
        agg_fsplit<HID><<<(N_NODES / 32) * (HID / 32), 256, 0, stream>>>(h, ell_col, cursor, dinv, g_hi, g_lo);
        const float* rs = (l == N_LAYERS - 2) ? nullptr : dinv;
        gemm_bias_relu<<<ggrid, 256, 0, stream>>>(g_hi, g_lo, WmT_h + (size_t)l * HID * HID,
                                                  WmT_l + (size_t)l * HID * HID,
                                                  bm + (size_t)l * HID, rs, h, N_NODES, HID, HID);
    }
    pool_kernel<<<(N_NODES + POOL_CHUNK - 1) / POOL_CHUNK, 256, 0, stream>>>(h, batch, pool_sum);
    final_linear_kernel<<<2, 256, 0, stream>>>(pool_sum, batch, Wlin, blin, outp);
}